// Round 10
// baseline (298.314 us; speedup 1.0000x reference)
//
#include <hip/hip_runtime.h>
#include <math.h>

// clDice loss on 32x1x512x512: sigmoid + dice + 10x soft-skeletonize + skel dice.
// R1: removed contended double atomics -> per-block partials (1059 -> 466 us).
// R3: fused 2 skeletonize iters/kernel via two-stage LDS (485 us, latency-bound).
// R5: 256 thr/block, 12 waves/CU (316 us).
// R7/8: fp16 global+LDS-B storage, fp32 math (262 us; VALU-instruction-bound on cvt).
// R9/R10: packed-fp16 stencil. R10 fix: ROCm 7.2 lacks __hmin2/__hmax2 here ->
//     use _Float16 ext_vector(2) + __builtin_elementwise_min/max (v_pk_min/max_f16)
//     and plain fma-contracted vector arithmetic (v_pk_fma_f16). cvt_pkrtz for packs.
//     min/max are exact selections on already-fp16 values; only blend rounds.

#define H 512
#define W 512
#define IMG (H * W)
#define NIMG 64
#define NPRED 32

#define AP 42      // LDS A pitch in pairs (uint=2 cols); pair p <-> tile cols (2p-8,2p-7); data p=2..37
#define AROWS 74   // row r <-> gy = tileY + r - 4 (data r 0..71)
#define BP 38      // LDS B pitch in pairs; pair p <-> tile cols (2p-4,2p-3); data p=0..35
#define BROWS 68   // row br <-> gy = tileY + br - 2

#define PINF_U 0x7C007C00u
#define NINF_U 0xFC00FC00u
#define ONE_U  0x3C003C00u

typedef _Float16 h2 __attribute__((ext_vector_type(2)));
typedef __fp16 fp16v2 __attribute__((ext_vector_type(2)));

__device__ __forceinline__ h2 H2(uint u) { return __builtin_bit_cast(h2, u); }
__device__ __forceinline__ uint U32(h2 h) { return __builtin_bit_cast(uint, h); }
__device__ __forceinline__ h2 min2(h2 a, h2 b) { return __builtin_elementwise_min(a, b); }
__device__ __forceinline__ h2 max2(h2 a, h2 b) { return __builtin_elementwise_max(a, b); }
// (a.hi, b.lo) -> one v_alignbit_b32
__device__ __forceinline__ h2 sh1(uint a, uint b) { return H2((b << 16) | (a >> 16)); }
__device__ __forceinline__ uint packrtz(float a, float b) {
    fp16v2 h = __builtin_amdgcn_cvt_pkrtz(a, b);
    return __builtin_bit_cast(uint, h);
}

__device__ __forceinline__ float wsum64(float v) {
#pragma unroll
    for (int o = 32; o > 0; o >>= 1) v += __shfl_down(v, o);
    return v;
}

// One row: S_k = 3-window mins as 4 aligned pairs (cols base-2..base+5, base = first
// stored col of this quad); C2/C3 = center pairs (cols base..base+3).
struct RowS { h2 S1, S2, S3, S4, C2, C3; };

__device__ __forceinline__ RowS rowmin(const uint* __restrict__ p) {
    uint2 a = *(const uint2*)p;        // cols base-4..base-1
    uint2 b = *(const uint2*)(p + 2);  // cols base..base+3 (center)
    uint2 c = *(const uint2*)(p + 4);  // cols base+4..base+7
    h2 Q1 = H2(a.y), Q2 = H2(b.x), Q3 = H2(b.y), Q4 = H2(c.x);
    h2 A1 = sh1(a.x, a.y), A2 = sh1(a.y, b.x), A3 = sh1(b.x, b.y),
       A4 = sh1(b.y, c.x), A5 = sh1(c.x, c.y);
    RowS r;
    r.S1 = min2(A1, min2(Q1, A2));
    r.S2 = min2(A2, min2(Q2, A3));
    r.S3 = min2(A3, min2(Q3, A4));
    r.S4 = min2(A4, min2(Q4, A5));
    r.C2 = Q2; r.C3 = Q3;
    return r;
}

struct ERow { h2 E1, E2, E3, E4; };  // eroded pairs, cols base-2..base+5

// vertical min of 3 S-rows + row-OOB mask + column edge masks (E1.hi = col base-1,
// E4.lo = col base+4 are the only consumed off-quad positions needing edge -inf).
__device__ __forceinline__ void evert(const RowS& a, const RowS& b, const RowS& c,
                                      bool rowok, bool mlo, bool mhi, ERow& e) {
    h2 ninf = H2(NINF_U);
    e.E1 = min2(a.S1, min2(b.S1, c.S1));
    e.E2 = min2(a.S2, min2(b.S2, c.S2));
    e.E3 = min2(a.S3, min2(b.S3, c.S3));
    e.E4 = min2(a.S4, min2(b.S4, c.S4));
    e.E1 = rowok ? e.E1 : ninf;
    e.E2 = rowok ? e.E2 : ninf;
    e.E3 = rowok ? e.E3 : ninf;
    e.E4 = rowok ? e.E4 : ninf;
    e.E1 = mlo ? H2((U32(e.E1) & 0x0000FFFFu) | 0xFC000000u) : e.E1;
    e.E4 = mhi ? H2((U32(e.E4) & 0xFFFF0000u) | 0x0000FC00u) : e.E4;
}

// horizontal 3-max of eroded row -> dilate pairs at cols base..base+3
__device__ __forceinline__ void dil(const ERow& e, h2& X2, h2& X3) {
    h2 B2 = sh1(U32(e.E1), U32(e.E2));
    h2 B3 = sh1(U32(e.E2), U32(e.E3));
    h2 B4 = sh1(U32(e.E3), U32(e.E4));
    X2 = max2(B2, max2(e.E2, B3));
    X3 = max2(B3, max2(e.E3, B4));
}

// o = clip(s + (e - s) * t, 0, 1), packed fp16 (fma-contracted)
__device__ __forceinline__ h2 blend(h2 s, h2 e, h2 t) {
    h2 o = (e - s) * t + s;
    o = max2(o, H2(0u));
    o = min2(o, H2(ONE_U));
    return o;
}

// ---- fills ----
// k_first: fp32 source (+optional sigmoid) -> packed A; fused dice partials over the
// interior (rows r 4..67, quads c 2..17 = exactly the 64x64 interior).
template<int PRED>
__device__ void fill_f32(uint* __restrict__ A, const float* __restrict__ src,
                         const float* __restrict__ tgt, int tileX, int tileY, int tid,
                         float& da, float& db) {
    for (int it = tid; it < AROWS * 20; it += 256) {
        int r = it / 20, c = it - r * 20;
        int gy = tileY + r - 4;
        int gx = tileX + 4 * c - 8;
        uint2 v = make_uint2(PINF_U, PINF_U);
        if ((unsigned)(c - 1) < 18u && (unsigned)gy < (unsigned)H &&
            (unsigned)gx < (unsigned)W) {
            float4 f = *(const float4*)(src + (size_t)gy * W + gx);
            if (PRED) {
                f.x = 1.0f / (1.0f + __expf(-f.x));
                f.y = 1.0f / (1.0f + __expf(-f.y));
                f.z = 1.0f / (1.0f + __expf(-f.z));
                f.w = 1.0f / (1.0f + __expf(-f.w));
            }
            v.x = packrtz(f.x, f.y);
            v.y = packrtz(f.z, f.w);
            if ((unsigned)(r - 4) < 64u && (unsigned)(c - 2) < 16u) {
                if (PRED) {
                    float4 t = *(const float4*)(tgt + (size_t)gy * W + gx);
                    da += f.x * t.x + f.y * t.y + f.z * t.z + f.w * t.w;
                    db += f.x + f.y + f.z + f.w;
                } else {
                    da += f.x + f.y + f.z + f.w;
                }
            }
        }
        *(uint2*)(A + r * AP + 2 * c) = v;
    }
}

// k_mid/k_last: packed fp16 global -> packed A (pure copy, no cvt).
__device__ void fill_h(uint* __restrict__ A, const uint* __restrict__ src,
                       int tileX, int tileY, int tid) {
    for (int it = tid; it < AROWS * 20; it += 256) {
        int r = it / 20, c = it - r * 20;
        int gy = tileY + r - 4;
        int gx = tileX + 4 * c - 8;
        uint2 v = make_uint2(PINF_U, PINF_U);
        if ((unsigned)(c - 1) < 18u && (unsigned)gy < (unsigned)H &&
            (unsigned)gx < (unsigned)W)
            v = *(const uint2*)(src + gy * (W / 2) + (gx >> 1));
        *(uint2*)(A + r * AP + 2 * c) = v;
    }
}

// Stage 1: one skeletonize iteration A -> B. 252 items = 14 strips(5 rows) x 18 quads.
__device__ void stage1(const uint* __restrict__ A, uint* __restrict__ B,
                       int tileX, int tileY, int tid) {
    for (int item = tid; item < 252; item += 256) {
        const int s = item / 18;
        const int q = item - s * 18;
        const int gX = tileX - 4 + 4 * q;      // first stored col (global, even)
        const int ys = tileY - 2 + 5 * s;      // first output row (global)
        const bool mlo = ((unsigned)(gX - 1) >= (unsigned)W);
        const bool mhi = ((unsigned)(gX + 4) >= (unsigned)W);
        const bool smA = ((unsigned)gX < (unsigned)W);       // pair cols gX,gX+1
        const bool smB = ((unsigned)(gX + 2) < (unsigned)W); // pair cols gX+2,gX+3
        const int lr = 5 * s + 2;              // A row of ys
        const uint* Ab = A + 2 * q;
        RowS rg[3]; ERow e;
        h2 X2r[3], X3r[3], ec2c, ec3c;
        rg[0] = rowmin(Ab + (lr - 2) * AP);
        rg[1] = rowmin(Ab + (lr - 1) * AP);
        rg[2] = rowmin(Ab + (lr + 0) * AP);
        evert(rg[0], rg[1], rg[2], (unsigned)(ys - 1) < (unsigned)H, mlo, mhi, e);
        dil(e, X2r[0], X3r[0]);
        rg[0] = rowmin(Ab + (lr + 1) * AP);
        evert(rg[1], rg[2], rg[0], (unsigned)ys < (unsigned)H, mlo, mhi, e);
        dil(e, X2r[1], X3r[1]);
        ec2c = e.E2; ec3c = e.E3;
#pragma unroll
        for (int k = 0; k < 5; k++) {
            rg[(k + 1) % 3] = rowmin(Ab + (lr + 2 + k) * AP);
            evert(rg[(k + 2) % 3], rg[k % 3], rg[(k + 1) % 3],
                  (unsigned)(ys + k + 1) < (unsigned)H, mlo, mhi, e);
            dil(e, X2r[(k + 2) % 3], X3r[(k + 2) % 3]);
            h2 t2 = max2(X2r[k % 3], max2(X2r[(k + 1) % 3], X2r[(k + 2) % 3]));
            h2 t3 = max2(X3r[k % 3], max2(X3r[(k + 1) % 3], X3r[(k + 2) % 3]));
            h2 o2 = blend(rg[(k + 2) % 3].C2, ec2c, t2);
            h2 o3 = blend(rg[(k + 2) % 3].C3, ec3c, t3);
            int br = 5 * s + k;
            if (br < BROWS) {
                bool rin = ((unsigned)(ys + k) < (unsigned)H);
                uint2 wv;
                wv.x = (rin && smA) ? U32(o2) : PINF_U;  // +inf outside: erosion-neutral
                wv.y = (rin && smB) ? U32(o3) : PINF_U;
                *(uint2*)(B + br * BP + 2 * q) = wv;
            }
            ec2c = e.E2; ec3c = e.E3;
        }
    }
}

// Stage 2: second iteration B -> interior 64x64 (packed global store or regs).
// 256 threads: 16 col-quads (tx) x 16 4-row strips (ty).
template<bool TOREG>
__device__ void stage2(const uint* __restrict__ B, int tileX, int tileY,
                       int tx, int ty, uint* __restrict__ gdst, h2 (*oreg)[2]) {
    const int X = tileX + 4 * tx;
    const int gy0 = tileY + 4 * ty;
    const int rb = 4 * ty + 2;
    const bool mlo = ((unsigned)(X - 1) >= (unsigned)W);
    const bool mhi = ((unsigned)(X + 4) >= (unsigned)W);
    const uint* Bb = B + 2 * tx;
    RowS rg[3]; ERow e;
    h2 X2r[3], X3r[3], ec2c, ec3c;
    rg[0] = rowmin(Bb + (rb - 2) * BP);
    rg[1] = rowmin(Bb + (rb - 1) * BP);
    rg[2] = rowmin(Bb + (rb + 0) * BP);
    evert(rg[0], rg[1], rg[2], (unsigned)(gy0 - 1) < (unsigned)H, mlo, mhi, e);
    dil(e, X2r[0], X3r[0]);
    rg[0] = rowmin(Bb + (rb + 1) * BP);
    evert(rg[1], rg[2], rg[0], (unsigned)gy0 < (unsigned)H, mlo, mhi, e);
    dil(e, X2r[1], X3r[1]);
    ec2c = e.E2; ec3c = e.E3;
#pragma unroll
    for (int k = 0; k < 4; k++) {
        rg[(k + 1) % 3] = rowmin(Bb + (rb + 2 + k) * BP);
        evert(rg[(k + 2) % 3], rg[k % 3], rg[(k + 1) % 3],
              (unsigned)(gy0 + k + 1) < (unsigned)H, mlo, mhi, e);
        dil(e, X2r[(k + 2) % 3], X3r[(k + 2) % 3]);
        h2 t2 = max2(X2r[k % 3], max2(X2r[(k + 1) % 3], X2r[(k + 2) % 3]));
        h2 t3 = max2(X3r[k % 3], max2(X3r[(k + 1) % 3], X3r[(k + 2) % 3]));
        h2 o2 = blend(rg[(k + 2) % 3].C2, ec2c, t2);
        h2 o3 = blend(rg[(k + 2) % 3].C3, ec3c, t3);
        if (TOREG) {
            oreg[k][0] = o2; oreg[k][1] = o3;
        } else {
            uint2 wv; wv.x = U32(o2); wv.y = U32(o3);
            *(uint2*)(gdst + (size_t)(gy0 + k) * (W / 2) + (X >> 1)) = wv;
        }
        ec2c = e.E2; ec3c = e.E3;
    }
}

// ---- K1: sigmoid + dice partials (fused in fill) + iters 1,2 ----
__global__ __launch_bounds__(256, 6) void k_first(
    const float* __restrict__ logits, const float* __restrict__ target,
    uint* __restrict__ outb, float* __restrict__ parts0, float* __restrict__ parts1) {
    __shared__ uint A[AROWS * AP];
    __shared__ uint B[BROWS * BP];
    __shared__ float red[8];
    const int img = blockIdx.z;
    const int tileX = blockIdx.x * 64, tileY = blockIdx.y * 64;
    const int tid = threadIdx.y * 16 + threadIdx.x;
    float a = 0.0f, b = 0.0f;
    if (img < NPRED)
        fill_f32<1>(A, logits + (size_t)img * IMG, target + (size_t)img * IMG,
                    tileX, tileY, tid, a, b);
    else
        fill_f32<0>(A, target + (size_t)(img - NPRED) * IMG, nullptr,
                    tileX, tileY, tid, a, b);
    a = wsum64(a); b = wsum64(b);
    if ((tid & 63) == 0) { red[tid >> 6] = a; red[4 + (tid >> 6)] = b; }
    __syncthreads();
    stage1(A, B, tileX, tileY, tid);
    __syncthreads();
    if (tid == 0) {
        int bi = blockIdx.z * 64 + blockIdx.y * 8 + blockIdx.x;
        parts0[bi] = red[0] + red[1] + red[2] + red[3];
        parts1[bi] = red[4] + red[5] + red[6] + red[7];
    }
    stage2<false>(B, tileX, tileY, threadIdx.x, threadIdx.y,
                  outb + (size_t)img * (IMG / 2), nullptr);
}

// ---- K2..K4: two iterations, packed buf -> packed buf ----
__global__ __launch_bounds__(256, 6) void k_mid(
    const uint* __restrict__ in, uint* __restrict__ outb) {
    __shared__ uint A[AROWS * AP];
    __shared__ uint B[BROWS * BP];
    const int img = blockIdx.z;
    const int tileX = blockIdx.x * 64, tileY = blockIdx.y * 64;
    const int tid = threadIdx.y * 16 + threadIdx.x;
    fill_h(A, in + (size_t)img * (IMG / 2), tileX, tileY, tid);
    __syncthreads();
    stage1(A, B, tileX, tileY, tid);
    __syncthreads();
    stage2<false>(B, tileX, tileY, threadIdx.x, threadIdx.y,
                  outb + (size_t)img * (IMG / 2), nullptr);
}

// ---- K5: iters 9,10 for pred tile AND matching target tile; skel-dice partials ----
__global__ __launch_bounds__(256, 6) void k_last(
    const uint* __restrict__ in, float* __restrict__ pA,
    float* __restrict__ pB, float* __restrict__ pC) {
    __shared__ uint A[AROWS * AP];
    __shared__ uint B[BROWS * BP];
    __shared__ float red[12];
    const int img = blockIdx.z;                  // 0..31
    const int tileX = blockIdx.x * 64, tileY = blockIdx.y * 64;
    const int tid = threadIdx.y * 16 + threadIdx.x;
    h2 op[4][2], ot[4][2];
    fill_h(A, in + (size_t)img * (IMG / 2), tileX, tileY, tid);
    __syncthreads();
    stage1(A, B, tileX, tileY, tid);
    __syncthreads();
    stage2<true>(B, tileX, tileY, threadIdx.x, threadIdx.y, nullptr, op);
    fill_h(A, in + (size_t)(img + NPRED) * (IMG / 2), tileX, tileY, tid);
    __syncthreads();   // orders stage2 B-reads before stage1 rewrites B
    stage1(A, B, tileX, tileY, tid);
    __syncthreads();
    stage2<true>(B, tileX, tileY, threadIdx.x, threadIdx.y, nullptr, ot);
    float a = 0.0f, b = 0.0f, c = 0.0f;
#pragma unroll
    for (int k = 0; k < 4; k++)
#pragma unroll
        for (int j = 0; j < 2; j++) {
            float px = (float)op[k][j].x, py = (float)op[k][j].y;
            float tx2 = (float)ot[k][j].x, ty2 = (float)ot[k][j].y;
            a += px * tx2 + py * ty2;
            b += px + py;
            c += tx2 + ty2;
        }
    a = wsum64(a); b = wsum64(b); c = wsum64(c);
    if ((tid & 63) == 0) {
        red[tid >> 6] = a; red[4 + (tid >> 6)] = b; red[8 + (tid >> 6)] = c;
    }
    __syncthreads();
    if (tid == 0) {
        int bi = img * 64 + blockIdx.y * 8 + blockIdx.x;
        pA[bi] = red[0] + red[1] + red[2] + red[3];
        pB[bi] = red[4] + red[5] + red[6] + red[7];
        pC[bi] = red[8] + red[9] + red[10] + red[11];
    }
}

// ---- per-image dice from 64 tile partials (1 wave per image) ----
__global__ __launch_bounds__(64) void finalize_img(
    const float* __restrict__ parts0, const float* __restrict__ parts1,
    const float* __restrict__ pA, const float* __restrict__ pB,
    const float* __restrict__ pC, float* __restrict__ dices) {
    const int i = blockIdx.x, t = threadIdx.x;
    float inter = wsum64(parts0[i * 64 + t]);
    float sp = wsum64(parts1[i * 64 + t]);
    float st = wsum64(parts0[(NPRED + i) * 64 + t]);
    float i2 = wsum64(pA[i * 64 + t]);
    float sp2 = wsum64(pB[i * 64 + t]);
    float st2 = wsum64(pC[i * 64 + t]);
    if (t == 0) {
        dices[i] = (float)((2.0 * (double)inter + 1e-5) / ((double)sp + (double)st + 1e-5));
        dices[32 + i] = (float)((2.0 * (double)i2 + 1e-5) / ((double)sp2 + (double)st2 + 1e-5));
    }
}

__global__ void finalize_out(const float* __restrict__ dices, float* __restrict__ out) {
    const int t = threadIdx.x;
    double d = 0.0, sd = 0.0;
    if (t < 32) { d = dices[t]; sd = dices[32 + t]; }
#pragma unroll
    for (int o = 32; o > 0; o >>= 1) { d += __shfl_down(d, o); sd += __shfl_down(sd, o); }
    if (t == 0) {
        d *= (1.0 / 32.0); sd *= (1.0 / 32.0);
        out[0] = (float)(0.5 * (1.0 - d) + 0.5 * (1.0 - sd));
        out[1] = (float)d;
        out[2] = (float)sd;
    }
}

extern "C" void kernel_launch(void* const* d_in, const int* in_sizes, int n_in,
                              void* d_out, int out_size, void* d_ws, size_t ws_size,
                              hipStream_t stream) {
    (void)in_sizes; (void)n_in; (void)out_size; (void)ws_size;
    const float* logits = (const float*)d_in[0];
    const float* target = (const float*)d_in[1];
    float* out = (float*)d_out;
    uint* buf0 = (uint*)d_ws;                       // 64 imgs * 131072 pairs (33.5 MB)
    uint* buf1 = buf0 + (size_t)NIMG * (IMG / 2);
    float* parts0 = (float*)(buf1 + (size_t)NIMG * (IMG / 2));  // 4096
    float* parts1 = parts0 + 4096;                  // 4096
    float* pA = parts1 + 4096;                      // 2048
    float* pB = pA + 2048;
    float* pC = pB + 2048;
    float* dices = pC + 2048;                       // 64

    dim3 blk(16, 16, 1);
    k_first<<<dim3(8, 8, NIMG), blk, 0, stream>>>(logits, target, buf0, parts0, parts1);
    k_mid<<<dim3(8, 8, NIMG), blk, 0, stream>>>(buf0, buf1);   // iters 3,4
    k_mid<<<dim3(8, 8, NIMG), blk, 0, stream>>>(buf1, buf0);   // iters 5,6
    k_mid<<<dim3(8, 8, NIMG), blk, 0, stream>>>(buf0, buf1);   // iters 7,8
    k_last<<<dim3(8, 8, NPRED), blk, 0, stream>>>(buf1, pA, pB, pC);  // iters 9,10 + partials
    finalize_img<<<32, 64, 0, stream>>>(parts0, parts1, pA, pB, pC, dices);
    finalize_out<<<1, 64, 0, stream>>>(dices, out);
}

// Round 11
// 291.147 us; speedup vs baseline: 1.0246x; 1.0246x over previous
//
#include <hip/hip_runtime.h>
#include <math.h>

// clDice loss on 32x1x512x512: sigmoid + dice + 10x soft-skeletonize + skel dice.
// R1: removed contended double atomics -> per-block partials (1059 -> 466 us).
// R3: fused 2 skeletonize iters/kernel via two-stage LDS (485 us).
// R5: 256 thr/block (316 us). R8: fp16 global + fp16 LDS-B, fp32 math (262 us).
// R10 FAILED (298): packed-h2 stencil scalarized by compiler (VALU busy unchanged),
//     wider pair windows; proved occupancy is NOT the limiter (59% occ, same busy).
// R11: revert to R8 math; keep only R10's proven-good parts: packed-fp16 LDS A read
//     via R8's hmin3h (22.8K LDS -> 7 blocks/CU), dice fused into k_first fill,
//     k_mid/k_last fill = pure uint2 copy (zero cvt in fill).

#define H 512
#define W 512
#define IMG (H * W)
#define NIMG 64
#define NPRED 32

#define AP 42      // LDS A pitch in uints (2 fp16 cols each); pair p=2c, c=0..19; data c=1..18
#define AROWS 74   // row r <-> gy = tileY + r - 4; data r 0..71, r 72,73 pad (+inf)
#define BP2 38     // LDS B pitch in uints; 36 data + 2 pad
#define BROWS 68   // row br <-> gy = tileY + br - 2

#define PINF_U 0x7C007C00u

typedef _Float16 f16;
typedef __fp16 fp16v2 __attribute__((ext_vector_type(2)));

__device__ __forceinline__ float2 unpack2(uint u) {
    fp16v2 h = __builtin_bit_cast(fp16v2, u);
    return make_float2((float)h.x, (float)h.y);
}
__device__ __forceinline__ uint pack2(float a, float b) {
    fp16v2 h = __builtin_amdgcn_cvt_pkrtz(a, b);
    return __builtin_bit_cast(uint, h);
}

__device__ __forceinline__ float wsum64(float v) {
#pragma unroll
    for (int o = 32; o > 0; o >>= 1) v += __shfl_down(v, o);
    return v;
}

// fp16-packed hmin: 3x ds_read_b64 + unpacks, fp32 scalar mins (R8-proven pattern).
// row points at the uint holding cols c-4,c-3 (c = quad base col). h[j] <-> col c-1+j.
__device__ __forceinline__ void hmin3h(const uint* __restrict__ row, float h[6],
                                       float4& q1out) {
    uint2 a = *(const uint2*)(row);       // cols c-4..c-1
    uint2 b = *(const uint2*)(row + 2);   // cols c..c+3
    uint2 d = *(const uint2*)(row + 4);   // cols c+4..c+7
    float2 p1 = unpack2(a.y);             // c-2, c-1
    float2 p2 = unpack2(b.x);             // c,   c+1
    float2 p3 = unpack2(b.y);             // c+2, c+3
    float2 p4 = unpack2(d.x);             // c+4, c+5
    q1out = make_float4(p2.x, p2.y, p3.x, p3.y);
    h[0] = fminf(p1.x, fminf(p1.y, p2.x));
    h[1] = fminf(p1.y, fminf(p2.x, p2.y));
    h[2] = fminf(p2.x, fminf(p2.y, p3.x));
    h[3] = fminf(p2.y, fminf(p3.x, p3.y));
    h[4] = fminf(p3.x, fminf(p3.y, p4.x));
    h[5] = fminf(p3.y, fminf(p4.x, p4.y));
}

__device__ __forceinline__ void erode1(const float a[6], const float b[6], const float c[6],
                                       bool rowok, const bool cm[6], float e[6]) {
#pragma unroll
    for (int j = 0; j < 6; j++) {
        float v = fminf(a[j], fminf(b[j], c[j]));
        e[j] = (rowok && cm[j]) ? v : -INFINITY;
    }
}

__device__ __forceinline__ void erode2(const float a[6], const float b[6], const float c[6],
                                       int gy, bool lo, bool ro, float e[6]) {
    bool oob = (gy < 0) || (gy >= H);
#pragma unroll
    for (int j = 0; j < 6; j++) {
        float v = fminf(a[j], fminf(b[j], c[j]));
        e[j] = oob ? -INFINITY : v;
    }
    if (lo) e[0] = -INFINITY;
    if (ro) e[5] = -INFINITY;
}

__device__ __forceinline__ void hmax1(const float e[6], float hx[4], float ec[4]) {
    hx[0] = fmaxf(e[0], fmaxf(e[1], e[2]));
    hx[1] = fmaxf(e[1], fmaxf(e[2], e[3]));
    hx[2] = fmaxf(e[2], fmaxf(e[3], e[4]));
    hx[3] = fmaxf(e[3], fmaxf(e[4], e[5]));
    ec[0] = e[1]; ec[1] = e[2]; ec[2] = e[3]; ec[3] = e[4];
}

// ---- fills ----
// k_first: fp32 source (+optional sigmoid) -> packed A; dice partials fused over the
// interior (rows r 4..67 x quads c 2..17 = exactly the 64x64 interior).
template<int PRED>
__device__ void fill_f32(uint* __restrict__ A, const float* __restrict__ src,
                         const float* __restrict__ tgt, int tileX, int tileY, int tid,
                         float& da, float& db) {
    for (int it = tid; it < AROWS * 20; it += 256) {
        int r = it / 20, c = it - r * 20;
        int gy = tileY + r - 4;
        int gx = tileX + 4 * c - 8;
        uint2 v = make_uint2(PINF_U, PINF_U);
        if ((unsigned)(c - 1) < 18u && (unsigned)gy < (unsigned)H &&
            (unsigned)gx < (unsigned)W) {
            float4 f = *(const float4*)(src + (size_t)gy * W + gx);
            if (PRED) {
                f.x = 1.0f / (1.0f + __expf(-f.x));
                f.y = 1.0f / (1.0f + __expf(-f.y));
                f.z = 1.0f / (1.0f + __expf(-f.z));
                f.w = 1.0f / (1.0f + __expf(-f.w));
            }
            v.x = pack2(f.x, f.y);
            v.y = pack2(f.z, f.w);
            if ((unsigned)(r - 4) < 64u && (unsigned)(c - 2) < 16u) {
                if (PRED) {
                    float4 t = *(const float4*)(tgt + (size_t)gy * W + gx);
                    da += f.x * t.x + f.y * t.y + f.z * t.z + f.w * t.w;
                    db += f.x + f.y + f.z + f.w;
                } else {
                    da += f.x + f.y + f.z + f.w;
                }
            }
        }
        *(uint2*)(A + r * AP + 2 * c) = v;
    }
}

// k_mid/k_last: packed fp16 global -> packed A (pure copy, no cvt).
__device__ void fill_h(uint* __restrict__ A, const uint* __restrict__ src,
                       int tileX, int tileY, int tid) {
    for (int it = tid; it < AROWS * 20; it += 256) {
        int r = it / 20, c = it - r * 20;
        int gy = tileY + r - 4;
        int gx = tileX + 4 * c - 8;
        uint2 v = make_uint2(PINF_U, PINF_U);
        if ((unsigned)(c - 1) < 18u && (unsigned)gy < (unsigned)H &&
            (unsigned)gx < (unsigned)W)
            v = *(const uint2*)(src + gy * (W / 2) + (gx >> 1));
        *(uint2*)(A + r * AP + 2 * c) = v;
    }
}

// Stage 1: one skeletonize iteration A(fp16) -> B(fp16). 252 items = 14 strips x 18 quads.
__device__ void stage1(const uint* __restrict__ A, uint* __restrict__ Bu,
                       int tileX, int tileY, int tid) {
    for (int item = tid; item < 252; item += 256) {
        const int s = item / 18;
        const int q = item - s * 18;
        const int gcb = tileX - 4 + 4 * q;     // output quad base col (global)
        const int ys = tileY - 2 + 5 * s;      // first output row (global)
        bool cm[6], sm[4];
#pragma unroll
        for (int j = 0; j < 6; j++) cm[j] = ((unsigned)(gcb - 1 + j) < (unsigned)W);
#pragma unroll
        for (int j = 0; j < 4; j++) sm[j] = ((unsigned)(gcb + j) < (unsigned)W);
        const int lr = 5 * s + 2;              // A row of ys
        const uint* Ab = A + 2 * q;            // uint of col gcb-4
        float hm[3][6], hx[3][4], e[6], ec_cur[4], ec_nxt[4];
        float4 scq[3], qd;
        hmin3h(Ab + (lr - 2) * AP, hm[0], qd);
        hmin3h(Ab + (lr - 1) * AP, hm[1], qd);
        hmin3h(Ab + (lr + 0) * AP, hm[2], scq[0]);
        erode1(hm[0], hm[1], hm[2], (unsigned)(ys - 1) < (unsigned)H, cm, e);
        hmax1(e, hx[0], ec_nxt);
        hmin3h(Ab + (lr + 1) * AP, hm[0], scq[1]);
        erode1(hm[1], hm[2], hm[0], (unsigned)ys < (unsigned)H, cm, e);
        hmax1(e, hx[1], ec_cur);
#pragma unroll
        for (int k = 0; k < 5; k++) {
            hmin3h(Ab + (lr + 2 + k) * AP, hm[(k + 1) % 3], scq[(2 + k) % 3]);
            erode1(hm[(k + 2) % 3], hm[k % 3], hm[(k + 1) % 3],
                   (unsigned)(ys + k + 1) < (unsigned)H, cm, e);
            hmax1(e, hx[(k + 2) % 3], ec_nxt);
            float t0 = fmaxf(hx[k % 3][0], fmaxf(hx[(k + 1) % 3][0], hx[(k + 2) % 3][0]));
            float t1 = fmaxf(hx[k % 3][1], fmaxf(hx[(k + 1) % 3][1], hx[(k + 2) % 3][1]));
            float t2 = fmaxf(hx[k % 3][2], fmaxf(hx[(k + 1) % 3][2], hx[(k + 2) % 3][2]));
            float t3 = fmaxf(hx[k % 3][3], fmaxf(hx[(k + 1) % 3][3], hx[(k + 2) % 3][3]));
            float4 sc = scq[k % 3];
            float o0 = fminf(fmaxf(sc.x - (sc.x - ec_cur[0]) * t0, 0.0f), 1.0f);
            float o1 = fminf(fmaxf(sc.y - (sc.y - ec_cur[1]) * t1, 0.0f), 1.0f);
            float o2 = fminf(fmaxf(sc.z - (sc.z - ec_cur[2]) * t2, 0.0f), 1.0f);
            float o3 = fminf(fmaxf(sc.w - (sc.w - ec_cur[3]) * t3, 0.0f), 1.0f);
            int br = 5 * s + k;
            if (br < BROWS) {
                bool rin = ((unsigned)(ys + k) < (unsigned)H);
                float v0 = (rin && sm[0]) ? o0 : INFINITY;  // +inf: erosion-neutral pad
                float v1 = (rin && sm[1]) ? o1 : INFINITY;
                float v2 = (rin && sm[2]) ? o2 : INFINITY;
                float v3 = (rin && sm[3]) ? o3 : INFINITY;
                uint2 wv;
                wv.x = pack2(v0, v1);
                wv.y = pack2(v2, v3);
                *(uint2*)(Bu + br * BP2 + 2 * q) = wv;
            }
            ec_cur[0] = ec_nxt[0]; ec_cur[1] = ec_nxt[1];
            ec_cur[2] = ec_nxt[2]; ec_cur[3] = ec_nxt[3];
        }
    }
}

// Stage 2: second iteration B(fp16) -> interior 64x64 (fp16 global or fp32 regs).
// 256 threads: 16 col-quads x 16 4-row strips. (Unchanged from R8.)
template<bool TOREG>
__device__ void stage2(const uint* __restrict__ Bu, int tileX, int tileY,
                       int tx, int ty, uint* __restrict__ gdst, float (*oreg)[4]) {
    const int X = tileX + 4 * tx;
    const int gy0 = tileY + 4 * ty;
    const int rb = 4 * ty + 2;
    const bool lo = (X == 0);
    const bool ro = (X + 4 >= W);
    const uint* Bb = Bu + 2 * tx;          // uint of tile-col 4tx-4
    float hm[3][6], hx[3][4], e[6], ec_cur[4], ec_nxt[4];
    float4 scq[3], qd;
    hmin3h(Bb + (rb - 2) * BP2, hm[0], qd);
    hmin3h(Bb + (rb - 1) * BP2, hm[1], qd);
    hmin3h(Bb + (rb + 0) * BP2, hm[2], scq[0]);
    erode2(hm[0], hm[1], hm[2], gy0 - 1, lo, ro, e);
    hmax1(e, hx[0], ec_nxt);
    hmin3h(Bb + (rb + 1) * BP2, hm[0], scq[1]);
    erode2(hm[1], hm[2], hm[0], gy0, lo, ro, e);
    hmax1(e, hx[1], ec_cur);
#pragma unroll
    for (int k = 0; k < 4; k++) {
        hmin3h(Bb + (rb + 2 + k) * BP2, hm[(k + 1) % 3], scq[(2 + k) % 3]);
        erode2(hm[(k + 2) % 3], hm[k % 3], hm[(k + 1) % 3], gy0 + k + 1, lo, ro, e);
        hmax1(e, hx[(k + 2) % 3], ec_nxt);
        float t0 = fmaxf(hx[k % 3][0], fmaxf(hx[(k + 1) % 3][0], hx[(k + 2) % 3][0]));
        float t1 = fmaxf(hx[k % 3][1], fmaxf(hx[(k + 1) % 3][1], hx[(k + 2) % 3][1]));
        float t2 = fmaxf(hx[k % 3][2], fmaxf(hx[(k + 1) % 3][2], hx[(k + 2) % 3][2]));
        float t3 = fmaxf(hx[k % 3][3], fmaxf(hx[(k + 1) % 3][3], hx[(k + 2) % 3][3]));
        float4 sc = scq[k % 3];
        float4 o;
        o.x = fminf(fmaxf(sc.x - (sc.x - ec_cur[0]) * t0, 0.0f), 1.0f);
        o.y = fminf(fmaxf(sc.y - (sc.y - ec_cur[1]) * t1, 0.0f), 1.0f);
        o.z = fminf(fmaxf(sc.z - (sc.z - ec_cur[2]) * t2, 0.0f), 1.0f);
        o.w = fminf(fmaxf(sc.w - (sc.w - ec_cur[3]) * t3, 0.0f), 1.0f);
        if (TOREG) {
            oreg[k][0] = o.x; oreg[k][1] = o.y; oreg[k][2] = o.z; oreg[k][3] = o.w;
        } else {
            uint2 w;
            w.x = pack2(o.x, o.y);
            w.y = pack2(o.z, o.w);
            *(uint2*)(gdst + (size_t)(gy0 + k) * (W / 2) + (X >> 1)) = w;
        }
        ec_cur[0] = ec_nxt[0]; ec_cur[1] = ec_nxt[1];
        ec_cur[2] = ec_nxt[2]; ec_cur[3] = ec_nxt[3];
    }
}

// ---- K1: sigmoid + dice partials (fused in fill) + iters 1,2 ----
__global__ __launch_bounds__(256, 7) void k_first(
    const float* __restrict__ logits, const float* __restrict__ target,
    uint* __restrict__ outb, float* __restrict__ parts0, float* __restrict__ parts1) {
    __shared__ uint A[AROWS * AP];
    __shared__ uint B[BROWS * BP2];
    __shared__ float red[8];
    const int img = blockIdx.z;
    const int tileX = blockIdx.x * 64, tileY = blockIdx.y * 64;
    const int tid = threadIdx.y * 16 + threadIdx.x;
    float a = 0.0f, b = 0.0f;
    if (img < NPRED)
        fill_f32<1>(A, logits + (size_t)img * IMG, target + (size_t)img * IMG,
                    tileX, tileY, tid, a, b);
    else
        fill_f32<0>(A, target + (size_t)(img - NPRED) * IMG, nullptr,
                    tileX, tileY, tid, a, b);
    a = wsum64(a); b = wsum64(b);
    if ((tid & 63) == 0) { red[tid >> 6] = a; red[4 + (tid >> 6)] = b; }
    __syncthreads();
    stage1(A, B, tileX, tileY, tid);
    __syncthreads();
    if (tid == 0) {
        int bi = blockIdx.z * 64 + blockIdx.y * 8 + blockIdx.x;
        parts0[bi] = red[0] + red[1] + red[2] + red[3];
        parts1[bi] = red[4] + red[5] + red[6] + red[7];
    }
    stage2<false>(B, tileX, tileY, threadIdx.x, threadIdx.y,
                  outb + (size_t)img * (IMG / 2), nullptr);
}

// ---- K2..K4: two iterations, packed buf -> packed buf ----
__global__ __launch_bounds__(256, 7) void k_mid(
    const uint* __restrict__ in, uint* __restrict__ outb) {
    __shared__ uint A[AROWS * AP];
    __shared__ uint B[BROWS * BP2];
    const int img = blockIdx.z;
    const int tileX = blockIdx.x * 64, tileY = blockIdx.y * 64;
    const int tid = threadIdx.y * 16 + threadIdx.x;
    fill_h(A, in + (size_t)img * (IMG / 2), tileX, tileY, tid);
    __syncthreads();
    stage1(A, B, tileX, tileY, tid);
    __syncthreads();
    stage2<false>(B, tileX, tileY, threadIdx.x, threadIdx.y,
                  outb + (size_t)img * (IMG / 2), nullptr);
}

// ---- K5: iters 9,10 for pred tile AND matching target tile; skel-dice partials ----
__global__ __launch_bounds__(256, 7) void k_last(
    const uint* __restrict__ in, float* __restrict__ pA,
    float* __restrict__ pB, float* __restrict__ pC) {
    __shared__ uint A[AROWS * AP];
    __shared__ uint B[BROWS * BP2];
    __shared__ float red[12];
    const int img = blockIdx.z;                  // 0..31
    const int tileX = blockIdx.x * 64, tileY = blockIdx.y * 64;
    const int tid = threadIdx.y * 16 + threadIdx.x;
    float op[4][4], ot[4][4];
    fill_h(A, in + (size_t)img * (IMG / 2), tileX, tileY, tid);
    __syncthreads();
    stage1(A, B, tileX, tileY, tid);
    __syncthreads();
    stage2<true>(B, tileX, tileY, threadIdx.x, threadIdx.y, nullptr, op);
    fill_h(A, in + (size_t)(img + NPRED) * (IMG / 2), tileX, tileY, tid);
    __syncthreads();   // orders stage2 B-reads before stage1 rewrites B
    stage1(A, B, tileX, tileY, tid);
    __syncthreads();
    stage2<true>(B, tileX, tileY, threadIdx.x, threadIdx.y, nullptr, ot);
    float a = 0.0f, b = 0.0f, c = 0.0f;
#pragma unroll
    for (int k = 0; k < 4; k++)
#pragma unroll
        for (int j = 0; j < 4; j++) {
            a += op[k][j] * ot[k][j];
            b += op[k][j];
            c += ot[k][j];
        }
    a = wsum64(a); b = wsum64(b); c = wsum64(c);
    if ((tid & 63) == 0) {
        red[tid >> 6] = a; red[4 + (tid >> 6)] = b; red[8 + (tid >> 6)] = c;
    }
    __syncthreads();
    if (tid == 0) {
        int bi = img * 64 + blockIdx.y * 8 + blockIdx.x;
        pA[bi] = red[0] + red[1] + red[2] + red[3];
        pB[bi] = red[4] + red[5] + red[6] + red[7];
        pC[bi] = red[8] + red[9] + red[10] + red[11];
    }
}

// ---- per-image dice from 64 tile partials (1 wave per image) ----
__global__ __launch_bounds__(64) void finalize_img(
    const float* __restrict__ parts0, const float* __restrict__ parts1,
    const float* __restrict__ pA, const float* __restrict__ pB,
    const float* __restrict__ pC, float* __restrict__ dices) {
    const int i = blockIdx.x, t = threadIdx.x;
    float inter = wsum64(parts0[i * 64 + t]);
    float sp = wsum64(parts1[i * 64 + t]);
    float st = wsum64(parts0[(NPRED + i) * 64 + t]);
    float i2 = wsum64(pA[i * 64 + t]);
    float sp2 = wsum64(pB[i * 64 + t]);
    float st2 = wsum64(pC[i * 64 + t]);
    if (t == 0) {
        dices[i] = (float)((2.0 * (double)inter + 1e-5) / ((double)sp + (double)st + 1e-5));
        dices[32 + i] = (float)((2.0 * (double)i2 + 1e-5) / ((double)sp2 + (double)st2 + 1e-5));
    }
}

__global__ void finalize_out(const float* __restrict__ dices, float* __restrict__ out) {
    const int t = threadIdx.x;
    double d = 0.0, sd = 0.0;
    if (t < 32) { d = dices[t]; sd = dices[32 + t]; }
#pragma unroll
    for (int o = 32; o > 0; o >>= 1) { d += __shfl_down(d, o); sd += __shfl_down(sd, o); }
    if (t == 0) {
        d *= (1.0 / 32.0); sd *= (1.0 / 32.0);
        out[0] = (float)(0.5 * (1.0 - d) + 0.5 * (1.0 - sd));
        out[1] = (float)d;
        out[2] = (float)sd;
    }
}

extern "C" void kernel_launch(void* const* d_in, const int* in_sizes, int n_in,
                              void* d_out, int out_size, void* d_ws, size_t ws_size,
                              hipStream_t stream) {
    (void)in_sizes; (void)n_in; (void)out_size; (void)ws_size;
    const float* logits = (const float*)d_in[0];
    const float* target = (const float*)d_in[1];
    float* out = (float*)d_out;
    uint* buf0 = (uint*)d_ws;                       // 64 imgs * 131072 uints (33.5 MB)
    uint* buf1 = buf0 + (size_t)NIMG * (IMG / 2);
    float* parts0 = (float*)(buf1 + (size_t)NIMG * (IMG / 2));  // 4096
    float* parts1 = parts0 + 4096;                  // 4096
    float* pA = parts1 + 4096;                      // 2048
    float* pB = pA + 2048;
    float* pC = pB + 2048;
    float* dices = pC + 2048;                       // 64

    dim3 blk(16, 16, 1);
    k_first<<<dim3(8, 8, NIMG), blk, 0, stream>>>(logits, target, buf0, parts0, parts1);
    k_mid<<<dim3(8, 8, NIMG), blk, 0, stream>>>(buf0, buf1);   // iters 3,4
    k_mid<<<dim3(8, 8, NIMG), blk, 0, stream>>>(buf1, buf0);   // iters 5,6
    k_mid<<<dim3(8, 8, NIMG), blk, 0, stream>>>(buf0, buf1);   // iters 7,8
    k_last<<<dim3(8, 8, NPRED), blk, 0, stream>>>(buf1, pA, pB, pC);  // iters 9,10 + partials
    finalize_img<<<32, 64, 0, stream>>>(parts0, parts1, pA, pB, pC, dices);
    finalize_out<<<1, 64, 0, stream>>>(dices, out);
}